// Round 4
// baseline (230.686 us; speedup 1.0000x reference)
//
#include <hip/hip_runtime.h>
#include <cstdint>
#include <cstddef>

typedef unsigned short u16;
typedef short short8 __attribute__((ext_vector_type(8)));
typedef float floatx4 __attribute__((ext_vector_type(4)));

#define DEVINL __device__ __forceinline__

static constexpr int BSZ = 8, SEQL = 4096, H = 512, P = 256;
static constexpr int M = BSZ * SEQL;       // 32768 rows
static constexpr int KD = 512;             // K for both GEMMs
static constexpr int ND = 512;             // N for both GEMMs
static constexpr int CHUNK = 32;
static constexpr int NCH = SEQL / CHUNK;   // 128 chunks

DEVINL u16 f2bf(float f) {
  union { float f; unsigned u; } v; v.f = f;
  unsigned r = (v.u + 0x7fffu + ((v.u >> 16) & 1u)) >> 16;
  return (u16)r;
}
DEVINL float bf2f(u16 h) {
  union { unsigned u; float f; } v; v.u = ((unsigned)h) << 16; return v.f;
}

// async global->LDS, 16B per lane. LDS dest must be wave-uniform base + lane*16.
DEVINL void gload_lds16(const u16* g, u16* l) {
  __builtin_amdgcn_global_load_lds(
      (const __attribute__((address_space(1))) unsigned*)g,
      (__attribute__((address_space(3))) unsigned*)l, 16, 0, 0);
}

// ---------- setup: lam[p] = exp(Lambda*step), f[p] = (lam-1)/Lambda ----------
__global__ void setup_kernel(const float* __restrict__ Lre, const float* __restrict__ Lim,
                             const float* __restrict__ logstep,
                             float2* __restrict__ lam, float2* __restrict__ ffac) {
  int p = threadIdx.x;
  if (p >= P) return;
  float lr = Lre[p], li = Lim[p];
  float st = expf(logstep[p]);
  float mag = expf(lr * st);
  float ang = li * st;
  float cr = mag * cosf(ang);
  float ci = mag * sinf(ang);
  lam[p] = make_float2(cr, ci);
  float a = cr - 1.0f, b = ci;
  float den = lr * lr + li * li;
  float fr = (a * lr + b * li) / den;
  float fi = (b * lr - a * li) / den;
  ffac[p] = make_float2(fr, fi);
}

// ---------- Bt1[n=2p+ri][h] = component of f[p]*B_tilde[p][h], bf16 ----------
__global__ void bt1_kernel(const float2* __restrict__ Bin,
                           const float2* __restrict__ ffac,
                           u16* __restrict__ bt1) {
  int idx = blockIdx.x * 256 + threadIdx.x;   // over P*H
  int p = idx / H, h = idx % H;
  float2 bv = Bin[(size_t)p * H + h];
  float2 f = ffac[p];
  float br = f.x * bv.x - f.y * bv.y;
  float bi = f.x * bv.y + f.y * bv.x;
  bt1[(size_t)(2 * p) * H + h]     = f2bf(br);
  bt1[(size_t)(2 * p + 1) * H + h] = f2bf(bi);
}

// ---------- Bt2[h][2p+ri] = +-2 * C[h][p][ri] ----------
__global__ void bt2_kernel(const float* __restrict__ Cin, u16* __restrict__ bt2) {
  int idx = blockIdx.x * 256 + threadIdx.x;   // over H*P*2
  float c = Cin[idx];
  float v = (idx & 1) ? -2.0f * c : 2.0f * c;
  bt2[idx] = f2bf(v);
}

// ---------- MFMA GEMM: C[M][N] = A[M][K]*Bt[N][K]^T ----------
// Tile 128(M) x 256(N), BK=32, 3-stage LDS pipeline, counted vmcnt.
// MODE 0: A = u in f32, reg-staged (load f32 -> cvt bf16 -> ds_write), so the
//         separate ucvt kernel and the ubf buffer are eliminated. B via gload_lds.
//         Per tile: 4 A-reg loads (float4) + 4 B gload_lds = 8 vm ops.
// MODE 1: A = xs bf16 via gload_lds (2) + B (4) = 6 vm ops; epilogue reads u f32.
// XCD swizzle: 512 blocks, 64/XCD; same-bm pairs share A-panel in one L2.
template <int MODE>
__global__ __launch_bounds__(256, 2) void gemm_bt(const u16* __restrict__ A,
                                                  const float* __restrict__ Af32,
                                                  const u16* __restrict__ Bt,
                                                  u16* __restrict__ outBf,
                                                  float* __restrict__ outF,
                                                  const float* __restrict__ Dv,
                                                  const float* __restrict__ U32) {
  __shared__ u16 As[3][128 * 32];   // 3 x 8 KB
  __shared__ u16 Bs[3][256 * 32];   // 3 x 16 KB   (72 KB total)
  const int tid = threadIdx.x;

  // XCD swizzle: 512 blocks, 8 XCDs, 64 logical tiles per XCD.
  const int hw = blockIdx.x;
  const int logical = (hw & 7) * 64 + (hw >> 3);
  const int bm = logical >> 1;        // 0..255
  const int bn = logical & 1;         // 0..1

  const int wave = tid >> 6, lane = tid & 63;
  const int quad = lane >> 4, l16 = lane & 15;
  const int wm = (wave & 1) << 6;           // 0 or 64   (2 waves over 128 rows)
  const int wn = (wave >> 1) << 7;          // 0 or 128  (2 waves over 256 cols)

  floatx4 acc[4][8] = {};

  const u16*   Ab  = (MODE == 0) ? nullptr : A + (size_t)bm * 128 * KD;
  const float* Afb = (MODE == 0) ? Af32 + (size_t)bm * 128 * KD : nullptr;
  const u16*   Bb  = Bt + (size_t)bn * 256 * KD;
  const int srow = tid >> 2;
  const int scol = (tid & 3) << 3;   // element offset within 32-wide row

  float4 aR[2][4];   // two in-flight A-reg sets (MODE 0); indices static via unroll

#define STAGE_B(buf, kofs)                                                                 \
  do {                                                                                     \
    gload_lds16(Bb + (size_t)srow * KD + (kofs) + scol,         &Bs[buf][tid * 8]);        \
    gload_lds16(Bb + (size_t)(srow + 64) * KD + (kofs) + scol,  &Bs[buf][2048 + tid * 8]); \
    gload_lds16(Bb + (size_t)(srow + 128) * KD + (kofs) + scol, &Bs[buf][4096 + tid * 8]); \
    gload_lds16(Bb + (size_t)(srow + 192) * KD + (kofs) + scol, &Bs[buf][6144 + tid * 8]); \
  } while (0)

#define STAGE_A_LDS(buf, kofs)                                                             \
  do {                                                                                     \
    gload_lds16(Ab + (size_t)srow * KD + (kofs) + scol,        &As[buf][tid * 8]);         \
    gload_lds16(Ab + (size_t)(srow + 64) * KD + (kofs) + scol, &As[buf][2048 + tid * 8]);  \
  } while (0)

#define ISSUE_A(set, kofs)                                                                 \
  do {                                                                                     \
    aR[set][0] = *(const float4*)(Afb + (size_t)srow * KD + (kofs) + scol);                \
    aR[set][1] = *(const float4*)(Afb + (size_t)srow * KD + (kofs) + scol + 4);            \
    aR[set][2] = *(const float4*)(Afb + (size_t)(srow + 64) * KD + (kofs) + scol);         \
    aR[set][3] = *(const float4*)(Afb + (size_t)(srow + 64) * KD + (kofs) + scol + 4);     \
  } while (0)

#define WRITE_A(set, buf)                                                                  \
  do {                                                                                     \
    short8 w0, w1;                                                                         \
    w0[0] = (short)f2bf(aR[set][0].x); w0[1] = (short)f2bf(aR[set][0].y);                  \
    w0[2] = (short)f2bf(aR[set][0].z); w0[3] = (short)f2bf(aR[set][0].w);                  \
    w0[4] = (short)f2bf(aR[set][1].x); w0[5] = (short)f2bf(aR[set][1].y);                  \
    w0[6] = (short)f2bf(aR[set][1].z); w0[7] = (short)f2bf(aR[set][1].w);                  \
    w1[0] = (short)f2bf(aR[set][2].x); w1[1] = (short)f2bf(aR[set][2].y);                  \
    w1[2] = (short)f2bf(aR[set][2].z); w1[3] = (short)f2bf(aR[set][2].w);                  \
    w1[4] = (short)f2bf(aR[set][3].x); w1[5] = (short)f2bf(aR[set][3].y);                  \
    w1[6] = (short)f2bf(aR[set][3].z); w1[7] = (short)f2bf(aR[set][3].w);                  \
    *(short8*)&As[buf][tid * 8]        = w0;                                               \
    *(short8*)&As[buf][2048 + tid * 8] = w1;                                               \
  } while (0)

#define VMW(n) asm volatile("s_waitcnt vmcnt(" #n ")" ::: "memory");                       \
               __builtin_amdgcn_sched_barrier(0)
#define LGKW   asm volatile("s_waitcnt lgkmcnt(0)" ::: "memory");                          \
               __builtin_amdgcn_sched_barrier(0)
#define BARR   __builtin_amdgcn_s_barrier();                                               \
               __builtin_amdgcn_sched_barrier(0)

  constexpr int NK = KD / 32;   // 16

  // ---- prologue: stage tiles 0 and 1 ----
  if constexpr (MODE == 0) {
    ISSUE_A(0, 0);
    STAGE_B(0, 0);
    ISSUE_A(1, 32);
    STAGE_B(1, 32);
    VMW(12);            // A0 landed
    WRITE_A(0, 0);
    VMW(8);             // B0 landed (A1,B1 in flight)
    LGKW;               // As[0] ds_writes visible
    BARR;
  } else {
    STAGE_A_LDS(0, 0);
    STAGE_B(0, 0);
    STAGE_A_LDS(1, 32);
    STAGE_B(1, 32);
    VMW(6);             // tile 0 landed
    BARR;
  }

#pragma unroll
  for (int ks = 0; ks < NK; ks++) {
    const int k0 = ks * 32;
    const int cur = ks % 3;
    const bool issue = (ks + 2 < NK);

    if constexpr (MODE == 0) {
      if (issue) {
        ISSUE_A(ks & 1, k0 + 64);
        STAGE_B((ks + 2) % 3, k0 + 64);
      }
    } else {
      if (issue) {
        STAGE_A_LDS((ks + 2) % 3, k0 + 64);
        STAGE_B((ks + 2) % 3, k0 + 64);
      }
    }

    short8 af[4], bfr[8];
#pragma unroll
    for (int t = 0; t < 4; t++)
      af[t] = *(const short8*)&As[cur][(wm + t * 16 + l16) * 32 + quad * 8];
#pragma unroll
    for (int t = 0; t < 8; t++)
      bfr[t] = *(const short8*)&Bs[cur][(wn + t * 16 + l16) * 32 + quad * 8];

    if constexpr (MODE == 0) {
      // convert+write next tile's A fragment (regs loaded last iter / prologue)
      if (ks + 1 < NK) {
        if (issue) { VMW(12); } else { VMW(4); }   // A(ks+1) = 4 oldest
        WRITE_A((ks + 1) & 1, (ks + 1) % 3);
      }
    }

    LGKW;   // ds_reads (and MODE0 ds_writes) drained

    __builtin_amdgcn_s_setprio(1);
#pragma unroll
    for (int tm = 0; tm < 4; tm++)
#pragma unroll
      for (int tn = 0; tn < 8; tn++)
        acc[tm][tn] = __builtin_amdgcn_mfma_f32_16x16x32_bf16(af[tm], bfr[tn], acc[tm][tn], 0, 0, 0);
    __builtin_amdgcn_s_setprio(0);

    if (ks + 1 < NK) {
      if constexpr (MODE == 0) {
        if (issue) { VMW(8); } else { VMW(0); }    // B(ks+1) landed
      } else {
        if (issue) { VMW(6); } else { VMW(0); }
      }
      BARR;
    }
  }
#undef STAGE_B
#undef STAGE_A_LDS
#undef ISSUE_A
#undef WRITE_A
#undef VMW
#undef LGKW
#undef BARR

  // epilogue: C/D layout col = lane&15, row = quad*4 + reg  [m89-verified]
  const int row_base = bm * 128 + wm + quad * 4;
  const int col_base = bn * 256 + wn + l16;
  float dv[8];
  if (MODE == 1) {
#pragma unroll
    for (int tn = 0; tn < 8; tn++) dv[tn] = Dv[col_base + tn * 16];
  }
#pragma unroll
  for (int tm = 0; tm < 4; tm++) {
#pragma unroll
    for (int tn = 0; tn < 8; tn++) {
      int n = col_base + tn * 16;
#pragma unroll
      for (int r = 0; r < 4; r++) {
        int m = row_base + tm * 16 + r;
        float v = acc[tm][tn][r];
        if (MODE == 0) {
          outBf[(size_t)m * ND + n] = f2bf(v);
        } else {
          float uv = U32[(size_t)m * ND + n];
          float ys = v + dv[tn] * uv;
          // gelu(ys) = ys * sigmoid(1.59577*(ys + 0.044715*ys^3)); exp via HW exp2
          float zz = ys + 0.044715f * (ys * ys * ys);
          float e = __builtin_amdgcn_exp2f(-2.3022082f * zz);
          outF[(size_t)m * ND + n] = ys * __builtin_amdgcn_rcpf(1.0f + e);
        }
      }
    }
  }
}

// ---------- scan pass 1: per-chunk carries ----------
__global__ __launch_bounds__(256) void scan_carry(const u16* __restrict__ Bu,
                                                  const float2* __restrict__ lam,
                                                  float2* __restrict__ carry) {
  int p = threadIdx.x;
  int c = blockIdx.x;
  int b = blockIdx.y;
  float2 lm = lam[p];
  float xr = 0.f, xi = 0.f;
  const u16* base = Bu + ((size_t)b * SEQL + (size_t)c * CHUNK) * 512 + 2 * p;
  for (int l = 0; l < CHUNK; l++) {
    unsigned w = *(const unsigned*)(base + (size_t)l * 512);
    float br = bf2f((u16)(w & 0xffffu));
    float bi = bf2f((u16)(w >> 16));
    float nr = lm.x * xr - lm.y * xi + br;
    float ni = lm.x * xi + lm.y * xr + bi;
    xr = nr; xi = ni;
  }
  carry[((size_t)b * NCH + c) * P + p] = make_float2(xr, xi);
}

// ---------- scan pass 2 (fused prefix+apply): each block redundantly combines its
// preceding carries (L2-resident, <=127 complex FMAs), then applies in-place ----------
__global__ __launch_bounds__(256) void scan_apply(u16* __restrict__ Bu,
                                                  const float2* __restrict__ lam,
                                                  const float2* __restrict__ carry) {
  int p = threadIdx.x;
  int c = blockIdx.x;
  int b = blockIdx.y;
  float2 lm = lam[p];
  // A = lm^CHUNK (CHUNK = 32 = 2^5)
  float ar = lm.x, ai = lm.y;
  for (int i = 0; i < 5; i++) { float nr = ar * ar - ai * ai, ni = 2.f * ar * ai; ar = nr; ai = ni; }
  // prefix for chunk c: p_0 = 0; p_{j+1} = A*p_j + carry_j
  float pr = 0.f, pi = 0.f;
  for (int j = 0; j < c; j++) {
    float2 ca = carry[((size_t)b * NCH + j) * P + p];
    float nr = ar * pr - ai * pi + ca.x;
    float ni = ar * pi + ai * pr + ca.y;
    pr = nr; pi = ni;
  }
  float xr = pr, xi = pi;
  u16* base = Bu + ((size_t)b * SEQL + (size_t)c * CHUNK) * 512 + 2 * p;
  for (int l = 0; l < CHUNK; l++) {
    unsigned* addr = (unsigned*)(base + (size_t)l * 512);
    unsigned w = *addr;
    float br = bf2f((u16)(w & 0xffffu));
    float bi = bf2f((u16)(w >> 16));
    float nr = lm.x * xr - lm.y * xi + br;
    float ni = lm.x * xi + lm.y * xr + bi;
    xr = nr; xi = ni;
    *addr = (unsigned)f2bf(nr) | ((unsigned)f2bf(ni) << 16);
  }
}

extern "C" void kernel_launch(void* const* d_in, const int* in_sizes, int n_in,
                              void* d_out, int out_size, void* d_ws, size_t ws_size,
                              hipStream_t stream) {
  const float* u      = (const float*)d_in[0];   // (8,4096,512)
  const float* Lre    = (const float*)d_in[1];   // (256,)
  const float* Lim    = (const float*)d_in[2];   // (256,)
  const float* Bin    = (const float*)d_in[3];   // (256,512,2)
  const float* Cin    = (const float*)d_in[4];   // (512,256,2)
  const float* Dv     = (const float*)d_in[5];   // (512,)
  const float* lstep  = (const float*)d_in[6];   // (256,1)
  float* out          = (float*)d_out;           // (8,4096,512) f32

  char* ws = (char*)d_ws;
  float2* lam    = (float2*)(ws + 0);                 //   2 KB
  float2* ffac   = (float2*)(ws + 2048);              //   2 KB
  u16*    bt1    = (u16*)   (ws + 4096);              // 512 KB
  u16*    bt2    = (u16*)   (ws + 528384);            // 512 KB
  u16*    Bu     = (u16*)   (ws + 1052672);           //  32 MB (becomes xs)
  float2* carry  = (float2*)(ws + 34607104);          //   2 MB

  setup_kernel<<<1, 256, 0, stream>>>(Lre, Lim, lstep, lam, ffac);
  bt1_kernel<<<(P * H) / 256, 256, 0, stream>>>((const float2*)Bin, ffac, bt1);
  bt2_kernel<<<(H * P * 2) / 256, 256, 0, stream>>>(Cin, bt2);

  gemm_bt<0><<<(M / 128) * (ND / 256), 256, 0, stream>>>(nullptr, u, bt1, Bu, nullptr, nullptr, nullptr);

  scan_carry <<<dim3(NCH, BSZ), 256, 0, stream>>>(Bu, lam, carry);
  scan_apply <<<dim3(NCH, BSZ), 256, 0, stream>>>(Bu, lam, carry);

  gemm_bt<1><<<(M / 128) * (ND / 256), 256, 0, stream>>>(Bu, nullptr, bt2, nullptr, out, Dv, u);
}

// Round 5
// 211.313 us; speedup vs baseline: 1.0917x; 1.0917x over previous
//
#include <hip/hip_runtime.h>
#include <cstdint>
#include <cstddef>

typedef unsigned short u16;
typedef short short8 __attribute__((ext_vector_type(8)));
typedef float floatx4 __attribute__((ext_vector_type(4)));

#define DEVINL __device__ __forceinline__

static constexpr int BSZ = 8, SEQL = 4096, H = 512, P = 256;
static constexpr int M = BSZ * SEQL;       // 32768 rows
static constexpr int KD = 512;             // K for both GEMMs
static constexpr int ND = 512;             // N for both GEMMs
static constexpr int CHUNK = 64;
static constexpr int NCH = SEQL / CHUNK;   // 64 chunks

DEVINL u16 f2bf(float f) {
  union { float f; unsigned u; } v; v.f = f;
  unsigned r = (v.u + 0x7fffu + ((v.u >> 16) & 1u)) >> 16;
  return (u16)r;
}
DEVINL float bf2f(u16 h) {
  union { unsigned u; float f; } v; v.u = ((unsigned)h) << 16; return v.f;
}

// async global->LDS, 16B per lane. LDS dest must be wave-uniform base + lane*16.
DEVINL void gload_lds16(const void* g, void* l) {
  __builtin_amdgcn_global_load_lds(
      (const __attribute__((address_space(1))) unsigned*)g,
      (__attribute__((address_space(3))) unsigned*)l, 16, 0, 0);
}

// ---------- setup: lam[p] = exp(Lambda*step), f[p] = (lam-1)/Lambda ----------
__global__ void setup_kernel(const float* __restrict__ Lre, const float* __restrict__ Lim,
                             const float* __restrict__ logstep,
                             float2* __restrict__ lam, float2* __restrict__ ffac) {
  int p = threadIdx.x;
  if (p >= P) return;
  float lr = Lre[p], li = Lim[p];
  float st = expf(logstep[p]);
  float mag = expf(lr * st);
  float ang = li * st;
  float cr = mag * cosf(ang);
  float ci = mag * sinf(ang);
  lam[p] = make_float2(cr, ci);
  float a = cr - 1.0f, b = ci;
  float den = lr * lr + li * li;
  float fr = (a * lr + b * li) / den;
  float fi = (b * lr - a * li) / den;
  ffac[p] = make_float2(fr, fi);
}

// ---------- Bt1[n=2p+ri][h] = component of f[p]*B_tilde[p][h], bf16 ----------
__global__ void bt1_kernel(const float2* __restrict__ Bin,
                           const float2* __restrict__ ffac,
                           u16* __restrict__ bt1) {
  int idx = blockIdx.x * 256 + threadIdx.x;   // over P*H
  int p = idx / H, h = idx % H;
  float2 bv = Bin[(size_t)p * H + h];
  float2 f = ffac[p];
  float br = f.x * bv.x - f.y * bv.y;
  float bi = f.x * bv.y + f.y * bv.x;
  bt1[(size_t)(2 * p) * H + h]     = f2bf(br);
  bt1[(size_t)(2 * p + 1) * H + h] = f2bf(bi);
}

// ---------- Bt2[h][2p+ri] = +-2 * C[h][p][ri] ----------
__global__ void bt2_kernel(const float* __restrict__ Cin, u16* __restrict__ bt2) {
  int idx = blockIdx.x * 256 + threadIdx.x;   // over H*P*2
  float c = Cin[idx];
  float v = (idx & 1) ? -2.0f * c : 2.0f * c;
  bt2[idx] = f2bf(v);
}

// ---------- GEMM0: Bu[M][N] = u[M][K](f32, cvt on the fly) * bt1[N][K]^T ----------
// R1 2-stage dbuf structure. A staged as f32 via global_load_lds (16 KB/tile),
// converted to bf16 fragments in VALU at LDS-read time -> no ucvt kernel, no ubf.
// LDS 48 KB -> 3 blocks/CU (same measured occupancy as R1's 32 KB @4).
__global__ __launch_bounds__(256, 3) void gemm0(const float* __restrict__ Af32,
                                                const u16* __restrict__ Bt,
                                                u16* __restrict__ outBf) {
  __shared__ float Asf[2][128 * 32];  // 2 x 16 KB
  __shared__ u16   Bs[2][128 * 32];   // 2 x 8 KB
  const int tid = threadIdx.x;
  const int bm = blockIdx.x, bn = blockIdx.y;
  const int wave = tid >> 6, lane = tid & 63;
  const int quad = lane >> 4, l16 = lane & 15;
  const int wm = (wave & 1) << 6, wn = (wave >> 1) << 6;

  floatx4 acc[4][4] = {};

  const float* Ab = Af32 + (size_t)bm * 128 * KD;
  const u16*   Bb = Bt + (size_t)bn * 128 * KD;
  // A staging (f32): thread tid covers (row = i*32 + tid>>3, 4-f32 chunk = tid&7)
  const int srowA = tid >> 3;
  const int scolA = (tid & 7) << 2;   // f32 offset within 32-wide row
  // B staging (bf16): row = j*64 + tid>>2, 8-u16 chunk = tid&3
  const int srowB = tid >> 2;
  const int scolB = (tid & 3) << 3;

#define STAGE0(buf, kofs)                                                                     \
  do {                                                                                        \
    gload_lds16(Ab + (size_t)srowA * KD + (kofs) + scolA,        &Asf[buf][tid * 4]);         \
    gload_lds16(Ab + (size_t)(srowA + 32) * KD + (kofs) + scolA, &Asf[buf][1024 + tid * 4]);  \
    gload_lds16(Ab + (size_t)(srowA + 64) * KD + (kofs) + scolA, &Asf[buf][2048 + tid * 4]);  \
    gload_lds16(Ab + (size_t)(srowA + 96) * KD + (kofs) + scolA, &Asf[buf][3072 + tid * 4]);  \
    gload_lds16(Bb + (size_t)srowB * KD + (kofs) + scolB,        &Bs[buf][tid * 8]);          \
    gload_lds16(Bb + (size_t)(srowB + 64) * KD + (kofs) + scolB, &Bs[buf][2048 + tid * 8]);   \
  } while (0)

  // prologue
  STAGE0(0, 0);
  asm volatile("s_waitcnt vmcnt(0)" ::: "memory");
  __builtin_amdgcn_sched_barrier(0);
  __builtin_amdgcn_s_barrier();

  int cur = 0;
  for (int k0 = 0; k0 < KD; k0 += 32) {
    if (k0 + 32 < KD) STAGE0(cur ^ 1, k0 + 32);

    short8 af[4], bfr[4];
#pragma unroll
    for (int t = 0; t < 4; t++) {
      const float* ap = &Asf[cur][(wm + t * 16 + l16) * 32 + quad * 8];
      float4 a0 = *(const float4*)ap;
      float4 a1 = *(const float4*)(ap + 4);
      af[t][0] = (short)f2bf(a0.x); af[t][1] = (short)f2bf(a0.y);
      af[t][2] = (short)f2bf(a0.z); af[t][3] = (short)f2bf(a0.w);
      af[t][4] = (short)f2bf(a1.x); af[t][5] = (short)f2bf(a1.y);
      af[t][6] = (short)f2bf(a1.z); af[t][7] = (short)f2bf(a1.w);
    }
#pragma unroll
    for (int t = 0; t < 4; t++)
      bfr[t] = *(const short8*)&Bs[cur][(wn + t * 16 + l16) * 32 + quad * 8];

    asm volatile("s_waitcnt lgkmcnt(0)" ::: "memory");
    __builtin_amdgcn_sched_barrier(0);

    __builtin_amdgcn_s_setprio(1);
#pragma unroll
    for (int tm = 0; tm < 4; tm++)
#pragma unroll
      for (int tn = 0; tn < 4; tn++)
        acc[tm][tn] = __builtin_amdgcn_mfma_f32_16x16x32_bf16(af[tm], bfr[tn], acc[tm][tn], 0, 0, 0);
    __builtin_amdgcn_s_setprio(0);

    asm volatile("s_waitcnt vmcnt(0)" ::: "memory");
    __builtin_amdgcn_sched_barrier(0);
    __builtin_amdgcn_s_barrier();
    cur ^= 1;
  }
#undef STAGE0

  // epilogue: C/D layout col = lane&15, row = quad*4 + reg  [m89-verified]
  const int row_base = bm * 128 + wm + quad * 4;
  const int col_base = bn * 128 + wn + l16;
#pragma unroll
  for (int tm = 0; tm < 4; tm++)
#pragma unroll
    for (int tn = 0; tn < 4; tn++) {
      int n = col_base + tn * 16;
#pragma unroll
      for (int r = 0; r < 4; r++) {
        int m = row_base + tm * 16 + r;
        outBf[(size_t)m * ND + n] = f2bf(acc[tm][tn][r]);
      }
    }
}

// ---------- GEMM1: ys = xs[M][K] * bt2[N][K]^T + D[n]*u, gelu -> f32 ----------
// Exact R1 MODE1 structure (2-stage dbuf, bf16 A via gload_lds); epilogue reads u f32.
__global__ __launch_bounds__(256, 4) void gemm1(const u16* __restrict__ A,
                                                const u16* __restrict__ Bt,
                                                float* __restrict__ outF,
                                                const float* __restrict__ Dv,
                                                const float* __restrict__ U32) {
  __shared__ u16 As[2][128 * 32];   // 2 x 8 KB
  __shared__ u16 Bs[2][128 * 32];   // 2 x 8 KB
  const int tid = threadIdx.x;
  const int bm = blockIdx.x, bn = blockIdx.y;
  const int wave = tid >> 6, lane = tid & 63;
  const int quad = lane >> 4, l16 = lane & 15;
  const int wm = (wave & 1) << 6, wn = (wave >> 1) << 6;

  floatx4 acc[4][4] = {};

  const u16* Ab = A + (size_t)bm * 128 * KD;
  const u16* Bb = Bt + (size_t)bn * 128 * KD;
  const int srow = tid >> 2;
  const int scol = (tid & 3) << 3;

#define STAGE1(buf, kofs)                                                                  \
  do {                                                                                     \
    gload_lds16(Ab + (size_t)srow * KD + (kofs) + scol,        &As[buf][tid * 8]);         \
    gload_lds16(Ab + (size_t)(srow + 64) * KD + (kofs) + scol, &As[buf][2048 + tid * 8]);  \
    gload_lds16(Bb + (size_t)srow * KD + (kofs) + scol,        &Bs[buf][tid * 8]);         \
    gload_lds16(Bb + (size_t)(srow + 64) * KD + (kofs) + scol, &Bs[buf][2048 + tid * 8]);  \
  } while (0)

  STAGE1(0, 0);
  asm volatile("s_waitcnt vmcnt(0)" ::: "memory");
  __builtin_amdgcn_sched_barrier(0);
  __builtin_amdgcn_s_barrier();

  int cur = 0;
  for (int k0 = 0; k0 < KD; k0 += 32) {
    if (k0 + 32 < KD) STAGE1(cur ^ 1, k0 + 32);

    short8 af[4], bfr[4];
#pragma unroll
    for (int t = 0; t < 4; t++)
      af[t] = *(const short8*)&As[cur][(wm + t * 16 + l16) * 32 + quad * 8];
#pragma unroll
    for (int t = 0; t < 4; t++)
      bfr[t] = *(const short8*)&Bs[cur][(wn + t * 16 + l16) * 32 + quad * 8];

    asm volatile("s_waitcnt lgkmcnt(0)" ::: "memory");
    __builtin_amdgcn_sched_barrier(0);

    __builtin_amdgcn_s_setprio(1);
#pragma unroll
    for (int tm = 0; tm < 4; tm++)
#pragma unroll
      for (int tn = 0; tn < 4; tn++)
        acc[tm][tn] = __builtin_amdgcn_mfma_f32_16x16x32_bf16(af[tm], bfr[tn], acc[tm][tn], 0, 0, 0);
    __builtin_amdgcn_s_setprio(0);

    asm volatile("s_waitcnt vmcnt(0)" ::: "memory");
    __builtin_amdgcn_sched_barrier(0);
    __builtin_amdgcn_s_barrier();
    cur ^= 1;
  }
#undef STAGE1

  const int row_base = bm * 128 + wm + quad * 4;
  const int col_base = bn * 128 + wn + l16;
  float dv[4];
#pragma unroll
  for (int tn = 0; tn < 4; tn++) dv[tn] = Dv[col_base + tn * 16];
#pragma unroll
  for (int tm = 0; tm < 4; tm++)
#pragma unroll
    for (int tn = 0; tn < 4; tn++) {
      int n = col_base + tn * 16;
#pragma unroll
      for (int r = 0; r < 4; r++) {
        int m = row_base + tm * 16 + r;
        float ys = acc[tm][tn][r] + dv[tn] * U32[(size_t)m * ND + n];
        // gelu(ys) = ys * sigmoid(1.59577*(ys + 0.044715*ys^3)); exp via HW exp2
        float zz = ys + 0.044715f * (ys * ys * ys);
        float e = __builtin_amdgcn_exp2f(-2.3022082f * zz);
        outF[(size_t)m * ND + n] = ys * __builtin_amdgcn_rcpf(1.0f + e);
      }
    }
}

// ---------- scan pass 1: per-chunk carries ----------
__global__ __launch_bounds__(256) void scan_carry(const u16* __restrict__ Bu,
                                                  const float2* __restrict__ lam,
                                                  float2* __restrict__ carry) {
  int p = threadIdx.x;
  int c = blockIdx.x;
  int b = blockIdx.y;
  float2 lm = lam[p];
  float xr = 0.f, xi = 0.f;
  const u16* base = Bu + ((size_t)b * SEQL + (size_t)c * CHUNK) * 512 + 2 * p;
  for (int l = 0; l < CHUNK; l++) {
    unsigned w = *(const unsigned*)(base + (size_t)l * 512);
    float br = bf2f((u16)(w & 0xffffu));
    float bi = bf2f((u16)(w >> 16));
    float nr = lm.x * xr - lm.y * xi + br;
    float ni = lm.x * xi + lm.y * xr + bi;
    xr = nr; xi = ni;
  }
  carry[((size_t)b * NCH + c) * P + p] = make_float2(xr, xi);
}

// ---------- scan pass 2: sequential prefix over chunks ----------
__global__ __launch_bounds__(256) void scan_prefix(const float2* __restrict__ carry,
                                                   const float2* __restrict__ lam,
                                                   float2* __restrict__ prefix) {
  int p = threadIdx.x;
  int b = blockIdx.x;
  float2 lm = lam[p];
  float ar = lm.x, ai = lm.y;
  for (int i = 0; i < 6; i++) { float nr = ar * ar - ai * ai, ni = 2.f * ar * ai; ar = nr; ai = ni; }
  float pr = 0.f, pi = 0.f;
  for (int c = 0; c < NCH; c++) {
    prefix[((size_t)b * NCH + c) * P + p] = make_float2(pr, pi);
    float2 ca = carry[((size_t)b * NCH + c) * P + p];
    float nr = ar * pr - ai * pi + ca.x;
    float ni = ar * pi + ai * pr + ca.y;
    pr = nr; pi = ni;
  }
}

// ---------- scan pass 3: apply prefix, write xs (bf16, in-place over Bu) ----------
__global__ __launch_bounds__(256) void scan_apply(u16* __restrict__ Bu,
                                                  const float2* __restrict__ lam,
                                                  const float2* __restrict__ prefix) {
  int p = threadIdx.x;
  int c = blockIdx.x;
  int b = blockIdx.y;
  float2 lm = lam[p];
  float2 pf = prefix[((size_t)b * NCH + c) * P + p];
  float xr = pf.x, xi = pf.y;
  u16* base = Bu + ((size_t)b * SEQL + (size_t)c * CHUNK) * 512 + 2 * p;
  for (int l = 0; l < CHUNK; l++) {
    unsigned* addr = (unsigned*)(base + (size_t)l * 512);
    unsigned w = *addr;
    float br = bf2f((u16)(w & 0xffffu));
    float bi = bf2f((u16)(w >> 16));
    float nr = lm.x * xr - lm.y * xi + br;
    float ni = lm.x * xi + lm.y * xr + bi;
    xr = nr; xi = ni;
    *addr = (unsigned)f2bf(nr) | ((unsigned)f2bf(ni) << 16);
  }
}

extern "C" void kernel_launch(void* const* d_in, const int* in_sizes, int n_in,
                              void* d_out, int out_size, void* d_ws, size_t ws_size,
                              hipStream_t stream) {
  const float* u      = (const float*)d_in[0];   // (8,4096,512)
  const float* Lre    = (const float*)d_in[1];   // (256,)
  const float* Lim    = (const float*)d_in[2];   // (256,)
  const float* Bin    = (const float*)d_in[3];   // (256,512,2)
  const float* Cin    = (const float*)d_in[4];   // (512,256,2)
  const float* Dv     = (const float*)d_in[5];   // (512,)
  const float* lstep  = (const float*)d_in[6];   // (256,1)
  float* out          = (float*)d_out;           // (8,4096,512) f32

  char* ws = (char*)d_ws;
  float2* lam    = (float2*)(ws + 0);                 //   2 KB
  float2* ffac   = (float2*)(ws + 2048);              //   2 KB
  u16*    bt1    = (u16*)   (ws + 4096);              // 512 KB
  u16*    bt2    = (u16*)   (ws + 528384);            // 512 KB
  u16*    Bu     = (u16*)   (ws + 1052672);           //  32 MB (becomes xs)
  float2* carry  = (float2*)(ws + 34607104);          //   1 MB
  float2* prefix = (float2*)(ws + 35655680);          //   1 MB

  setup_kernel<<<1, 256, 0, stream>>>(Lre, Lim, lstep, lam, ffac);
  bt1_kernel<<<(P * H) / 256, 256, 0, stream>>>((const float2*)Bin, ffac, bt1);
  bt2_kernel<<<(H * P * 2) / 256, 256, 0, stream>>>(Cin, bt2);

  gemm0<<<dim3(M / 128, ND / 128), 256, 0, stream>>>(u, bt1, Bu);

  scan_carry <<<dim3(NCH, BSZ), 256, 0, stream>>>(Bu, lam, carry);
  scan_prefix<<<BSZ, 256, 0, stream>>>(carry, lam, prefix);
  scan_apply <<<dim3(NCH, BSZ), 256, 0, stream>>>(Bu, lam, prefix);

  gemm1<<<dim3(M / 128, ND / 128), 256, 0, stream>>>(Bu, bt2, out, Dv, u);
}

// Round 6
// 208.492 us; speedup vs baseline: 1.1065x; 1.0135x over previous
//
#include <hip/hip_runtime.h>
#include <cstdint>
#include <cstddef>

typedef unsigned short u16;
typedef short short8 __attribute__((ext_vector_type(8)));
typedef float floatx4 __attribute__((ext_vector_type(4)));

#define DEVINL __device__ __forceinline__

static constexpr int BSZ = 8, SEQL = 4096, H = 512, P = 256;
static constexpr int M = BSZ * SEQL;       // 32768 rows
static constexpr int KD = 512;             // K for both GEMMs
static constexpr int ND = 512;             // N for both GEMMs
static constexpr int CHUNK = 64;
static constexpr int NCH = SEQL / CHUNK;   // 64 chunks

DEVINL u16 f2bf(float f) {
  union { float f; unsigned u; } v; v.f = f;
  unsigned r = (v.u + 0x7fffu + ((v.u >> 16) & 1u)) >> 16;
  return (u16)r;
}
DEVINL float bf2f(u16 h) {
  union { unsigned u; float f; } v; v.u = ((unsigned)h) << 16; return v.f;
}

// async global->LDS, 16B per lane. LDS dest must be wave-uniform base + lane*16.
DEVINL void gload_lds16(const void* g, void* l) {
  __builtin_amdgcn_global_load_lds(
      (const __attribute__((address_space(1))) unsigned*)g,
      (__attribute__((address_space(3))) unsigned*)l, 16, 0, 0);
}

// lam[p] = exp(Lambda[p] * step[p]), computed inline (replaces setup kernel)
DEVINL float2 lam_of(int p, const float* __restrict__ Lre, const float* __restrict__ Lim,
                     const float* __restrict__ lstep) {
  float lr = Lre[p], li = Lim[p];
  float st = expf(lstep[p]);
  float mag = expf(lr * st);
  float ang = li * st;
  return make_float2(mag * cosf(ang), mag * sinf(ang));
}

// ---------- prep: bt1 (f*B_tilde components) and bt2 (+-2C), one kernel ----------
// blocks [0,512): bt1 over P*H; blocks [512,1536): bt2 over H*P*2.
__global__ void prep_kernel(const float2* __restrict__ Bin, const float* __restrict__ Cin,
                            const float* __restrict__ Lre, const float* __restrict__ Lim,
                            const float* __restrict__ lstep,
                            u16* __restrict__ bt1, u16* __restrict__ bt2) {
  int bid = blockIdx.x;
  if (bid < 512) {
    int idx = bid * 256 + threadIdx.x;   // over P*H
    int p = idx / H, h = idx % H;
    // ffac[p] = (lam-1)/Lambda, inline (uniform p per block; redundant compute is trivial)
    float lr = Lre[p], li = Lim[p];
    float st = expf(lstep[p]);
    float mag = expf(lr * st);
    float ang = li * st;
    float cr = mag * cosf(ang), ci = mag * sinf(ang);
    float a = cr - 1.0f, b = ci;
    float den = lr * lr + li * li;
    float fr = (a * lr + b * li) / den;
    float fi = (b * lr - a * li) / den;
    float2 bv = Bin[(size_t)p * H + h];
    float br = fr * bv.x - fi * bv.y;
    float bi = fr * bv.y + fi * bv.x;
    bt1[(size_t)(2 * p) * H + h]     = f2bf(br);
    bt1[(size_t)(2 * p + 1) * H + h] = f2bf(bi);
  } else {
    int idx = (bid - 512) * 256 + threadIdx.x;   // over H*P*2
    float c = Cin[idx];
    float v = (idx & 1) ? -2.0f * c : 2.0f * c;
    bt2[idx] = f2bf(v);
  }
}

// ---------- GEMM0: Bu[M][N] = u[M][K](f32, cvt on the fly) * bt1[N][K]^T ----------
// A staged as f32 via global_load_lds with both-sides XOR chunk swizzle:
// LDS stays linear-dest (gload_lds requirement); SOURCE chunk = c_lds ^ (row&7);
// ds_read applies the same XOR -> each 16B slot hit by 2 lanes (free 2-way).
// Without this, f32 row stride (128B = 32 banks) put 16 lanes on one 4-bank group.
__global__ __launch_bounds__(256, 3) void gemm0(const float* __restrict__ Af32,
                                                const u16* __restrict__ Bt,
                                                u16* __restrict__ outBf) {
  __shared__ float Asf[2][128 * 32];  // 2 x 16 KB
  __shared__ u16   Bs[2][128 * 32];   // 2 x 8 KB
  const int tid = threadIdx.x;
  const int bm = blockIdx.x, bn = blockIdx.y;
  const int wave = tid >> 6, lane = tid & 63;
  const int quad = lane >> 4, l16 = lane & 15;
  const int wm = (wave & 1) << 6, wn = (wave >> 1) << 6;

  floatx4 acc[4][4] = {};

  const float* Ab = Af32 + (size_t)bm * 128 * KD;
  const u16*   Bb = Bt + (size_t)bn * 128 * KD;
  // A staging (f32): thread tid covers (row = g*32 + tid>>3, 16B chunk c_lds = tid&7).
  // Source chunk is inverse-swizzled: c_g = c_lds ^ (row&7); row&7 == (tid>>3)&7 for all g.
  const int srowA = tid >> 3;
  const int scolA = (((tid & 7) ^ ((tid >> 3) & 7)) << 2);   // f32 offset, swizzled
  // B staging (bf16): row = j*64 + tid>>2, 8-u16 chunk = tid&3 (unswizzled; benign 2-way)
  const int srowB = tid >> 2;
  const int scolB = (tid & 3) << 3;

#define STAGE0(buf, kofs)                                                                     \
  do {                                                                                        \
    gload_lds16(Ab + (size_t)srowA * KD + (kofs) + scolA,        &Asf[buf][tid * 4]);         \
    gload_lds16(Ab + (size_t)(srowA + 32) * KD + (kofs) + scolA, &Asf[buf][1024 + tid * 4]);  \
    gload_lds16(Ab + (size_t)(srowA + 64) * KD + (kofs) + scolA, &Asf[buf][2048 + tid * 4]);  \
    gload_lds16(Ab + (size_t)(srowA + 96) * KD + (kofs) + scolA, &Asf[buf][3072 + tid * 4]);  \
    gload_lds16(Bb + (size_t)srowB * KD + (kofs) + scolB,        &Bs[buf][tid * 8]);          \
    gload_lds16(Bb + (size_t)(srowB + 64) * KD + (kofs) + scolB, &Bs[buf][2048 + tid * 8]);   \
  } while (0)

  // prologue
  STAGE0(0, 0);
  asm volatile("s_waitcnt vmcnt(0)" ::: "memory");
  __builtin_amdgcn_sched_barrier(0);
  __builtin_amdgcn_s_barrier();

  // read-side swizzled chunk index: rows r = wm + t*16 + l16 -> r&7 == l16&7 (wm,t*16 ≡ 0 mod 8)
  const int c0 = ((quad << 1) ^ (l16 & 7));   // LDS chunk holding global chunk 2*quad
  const int c1 = c0 ^ 1;                      // LDS chunk holding global chunk 2*quad+1

  int cur = 0;
  for (int k0 = 0; k0 < KD; k0 += 32) {
    if (k0 + 32 < KD) STAGE0(cur ^ 1, k0 + 32);

    short8 af[4], bfr[4];
#pragma unroll
    for (int t = 0; t < 4; t++) {
      const float* rowp = &Asf[cur][(wm + t * 16 + l16) * 32];
      float4 a0 = *(const float4*)(rowp + c0 * 4);
      float4 a1 = *(const float4*)(rowp + c1 * 4);
      af[t][0] = (short)f2bf(a0.x); af[t][1] = (short)f2bf(a0.y);
      af[t][2] = (short)f2bf(a0.z); af[t][3] = (short)f2bf(a0.w);
      af[t][4] = (short)f2bf(a1.x); af[t][5] = (short)f2bf(a1.y);
      af[t][6] = (short)f2bf(a1.z); af[t][7] = (short)f2bf(a1.w);
    }
#pragma unroll
    for (int t = 0; t < 4; t++)
      bfr[t] = *(const short8*)&Bs[cur][(wn + t * 16 + l16) * 32 + quad * 8];

    asm volatile("s_waitcnt lgkmcnt(0)" ::: "memory");
    __builtin_amdgcn_sched_barrier(0);

    __builtin_amdgcn_s_setprio(1);
#pragma unroll
    for (int tm = 0; tm < 4; tm++)
#pragma unroll
      for (int tn = 0; tn < 4; tn++)
        acc[tm][tn] = __builtin_amdgcn_mfma_f32_16x16x32_bf16(af[tm], bfr[tn], acc[tm][tn], 0, 0, 0);
    __builtin_amdgcn_s_setprio(0);

    asm volatile("s_waitcnt vmcnt(0)" ::: "memory");
    __builtin_amdgcn_sched_barrier(0);
    __builtin_amdgcn_s_barrier();
    cur ^= 1;
  }
#undef STAGE0

  // epilogue: C/D layout col = lane&15, row = quad*4 + reg  [m89-verified]
  const int row_base = bm * 128 + wm + quad * 4;
  const int col_base = bn * 128 + wn + l16;
#pragma unroll
  for (int tm = 0; tm < 4; tm++)
#pragma unroll
    for (int tn = 0; tn < 4; tn++) {
      int n = col_base + tn * 16;
#pragma unroll
      for (int r = 0; r < 4; r++) {
        int m = row_base + tm * 16 + r;
        outBf[(size_t)m * ND + n] = f2bf(acc[tm][tn][r]);
      }
    }
}

// ---------- GEMM1: ys = xs[M][K] * bt2[N][K]^T + D[n]*u, gelu -> f32 ----------
__global__ __launch_bounds__(256, 4) void gemm1(const u16* __restrict__ A,
                                                const u16* __restrict__ Bt,
                                                float* __restrict__ outF,
                                                const float* __restrict__ Dv,
                                                const float* __restrict__ U32) {
  __shared__ u16 As[2][128 * 32];   // 2 x 8 KB
  __shared__ u16 Bs[2][128 * 32];   // 2 x 8 KB
  const int tid = threadIdx.x;
  const int bm = blockIdx.x, bn = blockIdx.y;
  const int wave = tid >> 6, lane = tid & 63;
  const int quad = lane >> 4, l16 = lane & 15;
  const int wm = (wave & 1) << 6, wn = (wave >> 1) << 6;

  floatx4 acc[4][4] = {};

  const u16* Ab = A + (size_t)bm * 128 * KD;
  const u16* Bb = Bt + (size_t)bn * 128 * KD;
  const int srow = tid >> 2;
  const int scol = (tid & 3) << 3;

#define STAGE1(buf, kofs)                                                                  \
  do {                                                                                     \
    gload_lds16(Ab + (size_t)srow * KD + (kofs) + scol,        &As[buf][tid * 8]);         \
    gload_lds16(Ab + (size_t)(srow + 64) * KD + (kofs) + scol, &As[buf][2048 + tid * 8]);  \
    gload_lds16(Bb + (size_t)srow * KD + (kofs) + scol,        &Bs[buf][tid * 8]);         \
    gload_lds16(Bb + (size_t)(srow + 64) * KD + (kofs) + scol, &Bs[buf][2048 + tid * 8]);  \
  } while (0)

  STAGE1(0, 0);
  asm volatile("s_waitcnt vmcnt(0)" ::: "memory");
  __builtin_amdgcn_sched_barrier(0);
  __builtin_amdgcn_s_barrier();

  int cur = 0;
  for (int k0 = 0; k0 < KD; k0 += 32) {
    if (k0 + 32 < KD) STAGE1(cur ^ 1, k0 + 32);

    short8 af[4], bfr[4];
#pragma unroll
    for (int t = 0; t < 4; t++)
      af[t] = *(const short8*)&As[cur][(wm + t * 16 + l16) * 32 + quad * 8];
#pragma unroll
    for (int t = 0; t < 4; t++)
      bfr[t] = *(const short8*)&Bs[cur][(wn + t * 16 + l16) * 32 + quad * 8];

    asm volatile("s_waitcnt lgkmcnt(0)" ::: "memory");
    __builtin_amdgcn_sched_barrier(0);

    __builtin_amdgcn_s_setprio(1);
#pragma unroll
    for (int tm = 0; tm < 4; tm++)
#pragma unroll
      for (int tn = 0; tn < 4; tn++)
        acc[tm][tn] = __builtin_amdgcn_mfma_f32_16x16x32_bf16(af[tm], bfr[tn], acc[tm][tn], 0, 0, 0);
    __builtin_amdgcn_s_setprio(0);

    asm volatile("s_waitcnt vmcnt(0)" ::: "memory");
    __builtin_amdgcn_sched_barrier(0);
    __builtin_amdgcn_s_barrier();
    cur ^= 1;
  }
#undef STAGE1

  const int row_base = bm * 128 + wm + quad * 4;
  const int col_base = bn * 128 + wn + l16;
  float dv[4];
#pragma unroll
  for (int tn = 0; tn < 4; tn++) dv[tn] = Dv[col_base + tn * 16];
#pragma unroll
  for (int tm = 0; tm < 4; tm++)
#pragma unroll
    for (int tn = 0; tn < 4; tn++) {
      int n = col_base + tn * 16;
#pragma unroll
      for (int r = 0; r < 4; r++) {
        int m = row_base + tm * 16 + r;
        float ys = acc[tm][tn][r] + dv[tn] * U32[(size_t)m * ND + n];
        // gelu(ys) = ys * sigmoid(1.59577*(ys + 0.044715*ys^3)); exp via HW exp2
        float zz = ys + 0.044715f * (ys * ys * ys);
        float e = __builtin_amdgcn_exp2f(-2.3022082f * zz);
        outF[(size_t)m * ND + n] = ys * __builtin_amdgcn_rcpf(1.0f + e);
      }
    }
}

// ---------- scan pass 1: per-chunk carries (lam inline) ----------
__global__ __launch_bounds__(256) void scan_carry(const u16* __restrict__ Bu,
                                                  const float* __restrict__ Lre,
                                                  const float* __restrict__ Lim,
                                                  const float* __restrict__ lstep,
                                                  float2* __restrict__ carry) {
  int p = threadIdx.x;
  int c = blockIdx.x;
  int b = blockIdx.y;
  float2 lm = lam_of(p, Lre, Lim, lstep);
  float xr = 0.f, xi = 0.f;
  const u16* base = Bu + ((size_t)b * SEQL + (size_t)c * CHUNK) * 512 + 2 * p;
  for (int l = 0; l < CHUNK; l++) {
    unsigned w = *(const unsigned*)(base + (size_t)l * 512);
    float br = bf2f((u16)(w & 0xffffu));
    float bi = bf2f((u16)(w >> 16));
    float nr = lm.x * xr - lm.y * xi + br;
    float ni = lm.x * xi + lm.y * xr + bi;
    xr = nr; xi = ni;
  }
  carry[((size_t)b * NCH + c) * P + p] = make_float2(xr, xi);
}

// ---------- scan pass 2 (fused prefix+apply): batched-ILP prefix over carries,
// then apply in-place. 16-wide load batches keep the L2 loads independent
// (R4's regression was a serial dependent-load chain; this amortizes latency). ----------
__global__ __launch_bounds__(256) void scan_apply(u16* __restrict__ Bu,
                                                  const float* __restrict__ Lre,
                                                  const float* __restrict__ Lim,
                                                  const float* __restrict__ lstep,
                                                  const float2* __restrict__ carry) {
  int p = threadIdx.x;
  int c = blockIdx.x;
  int b = blockIdx.y;
  float2 lm = lam_of(p, Lre, Lim, lstep);
  // A = lm^CHUNK (CHUNK = 64 = 2^6)
  float ar = lm.x, ai = lm.y;
  for (int i = 0; i < 6; i++) { float nr = ar * ar - ai * ai, ni = 2.f * ar * ai; ar = nr; ai = ni; }
  // prefix_c = recurrence p <- A*p + carry_j over j in [0,c), same fma order as before
  float pr = 0.f, pi = 0.f;
  const float2* cb_base = carry + (size_t)b * NCH * P + p;
  for (int j0 = 0; j0 < c; j0 += 16) {
    float2 cb[16];
#pragma unroll
    for (int t = 0; t < 16; t++) {
      int j = j0 + t;
      int jc = j < c ? j : c - 1;          // clamp address (loop entered => c >= 1)
      cb[t] = cb_base[(size_t)jc * P];
    }
#pragma unroll
    for (int t = 0; t < 16; t++) {
      bool real = (j0 + t) < c;
      float mr = real ? ar : 1.0f;
      float mi = real ? ai : 0.0f;
      float cx = real ? cb[t].x : 0.0f;
      float cy = real ? cb[t].y : 0.0f;
      float nr = mr * pr - mi * pi + cx;
      float ni = mr * pi + mi * pr + cy;
      pr = nr; pi = ni;
    }
  }
  float xr = pr, xi = pi;
  u16* base = Bu + ((size_t)b * SEQL + (size_t)c * CHUNK) * 512 + 2 * p;
  for (int l = 0; l < CHUNK; l++) {
    unsigned* addr = (unsigned*)(base + (size_t)l * 512);
    unsigned w = *addr;
    float br = bf2f((u16)(w & 0xffffu));
    float bi = bf2f((u16)(w >> 16));
    float nr = lm.x * xr - lm.y * xi + br;
    float ni = lm.x * xi + lm.y * xr + bi;
    xr = nr; xi = ni;
    *addr = (unsigned)f2bf(nr) | ((unsigned)f2bf(ni) << 16);
  }
}

extern "C" void kernel_launch(void* const* d_in, const int* in_sizes, int n_in,
                              void* d_out, int out_size, void* d_ws, size_t ws_size,
                              hipStream_t stream) {
  const float* u      = (const float*)d_in[0];   // (8,4096,512)
  const float* Lre    = (const float*)d_in[1];   // (256,)
  const float* Lim    = (const float*)d_in[2];   // (256,)
  const float* Bin    = (const float*)d_in[3];   // (256,512,2)
  const float* Cin    = (const float*)d_in[4];   // (512,256,2)
  const float* Dv     = (const float*)d_in[5];   // (512,)
  const float* lstep  = (const float*)d_in[6];   // (256,1)
  float* out          = (float*)d_out;           // (8,4096,512) f32

  char* ws = (char*)d_ws;
  u16*    bt1    = (u16*)   (ws + 0);                 // 512 KB
  u16*    bt2    = (u16*)   (ws + 524288);            // 512 KB
  u16*    Bu     = (u16*)   (ws + 1048576);           //  32 MB (becomes xs)
  float2* carry  = (float2*)(ws + 34603008);          //   1 MB

  prep_kernel<<<1536, 256, 0, stream>>>((const float2*)Bin, Cin, Lre, Lim, lstep, bt1, bt2);

  gemm0<<<dim3(M / 128, ND / 128), 256, 0, stream>>>(u, bt1, Bu);

  scan_carry<<<dim3(NCH, BSZ), 256, 0, stream>>>(Bu, Lre, Lim, lstep, carry);
  scan_apply<<<dim3(NCH, BSZ), 256, 0, stream>>>(Bu, Lre, Lim, lstep, carry);

  gemm1<<<dim3(M / 128, ND / 128), 256, 0, stream>>>(Bu, bt2, out, Dv, u);
}